// Round 18
// baseline (185.349 us; speedup 1.0000x reference)
//
#include <hip/hip_runtime.h>

#define Bn 64
#define Cc 384
#define NHh 6
#define HD 64
#define Hh 32
#define Ww 32
#define LQ 1025
#define LKV 257
#define TPAD 288
#define EPSf 1e-5f
#define SCALEf 0.05103103630798288f   // 384^-0.5

typedef float f32x4 __attribute__((ext_vector_type(4)));
typedef unsigned short u16x8 __attribute__((ext_vector_type(8)));
typedef unsigned short u16x4 __attribute__((ext_vector_type(4)));
typedef int i32x4 __attribute__((ext_vector_type(4)));

__device__ __forceinline__ void mfma_16x16x32_bf16(f32x4& d, u16x8 a, u16x8 b) {
  // D = A*B + D ; A: 16x32, row = lane&15, k = (lane>>4)*8 + i (contig 8)
  //              B: 32x16, col = lane&15, k = (lane>>4)*8 + i
  //              D: col = lane&15, row = (lane>>4)*4 + reg
  asm("v_mfma_f32_16x16x32_bf16 %0, %1, %2, %0" : "+v"(d) : "v"(a), "v"(b));
}

__device__ __forceinline__ unsigned short f2bf(float f) {
  unsigned int u = __builtin_bit_cast(unsigned int, f);
  u += 0x7fffu + ((u >> 16) & 1u);
  return (unsigned short)(u >> 16);
}

__device__ __forceinline__ u16x4 f4tobf(f32x4 v, f32x4 inv, f32x4 add) {
  u16x4 r;
#pragma unroll
  for (int i = 0; i < 4; ++i) r[i] = f2bf(v[i] * inv[i] + add[i]);
  return r;
}

// ---------------- merged prep: weight cvt + conv-w prep + cls -----------------
__global__ void prep_kernel(const float* hidden,
                            const float* wq, const float* wk, const float* wv,
                            const float* cwq, const float* cwk, const float* cwv,
                            const float* gq, const float* bq, const float* mq, const float* vq,
                            const float* gk, const float* bk, const float* mk, const float* vk,
                            const float* gv, const float* bv, const float* mv, const float* vv,
                            unsigned short* wbf, float* wT, float* bn,
                            unsigned short* q_act, unsigned short* k_act,
                            unsigned short* v_act) {
  int i = blockIdx.x * 256 + threadIdx.x;            // grid = 3*Cc*Cc = 442368
  if (i < 3 * Cc * Cc) {                              // GEMM weights -> bf16
    int which = i / (Cc * Cc), r = i % (Cc * Cc);
    const float* s = (which == 0) ? wq : (which == 1) ? wk : wv;
    wbf[i] = f2bf(s[r]);
  }
  if (i < 3 * 9 * Cc) {                               // conv weight transpose
    int which = i / (9 * Cc), r = i % (9 * Cc), t = r / Cc, c = r % Cc;
    const float* s = (which == 0) ? cwq : (which == 1) ? cwk : cwv;
    wT[(which * 9 + t) * Cc + c] = s[c * 9 + t];
  }
  if (i < 3 * Cc) {                                   // BN fold
    int which = i / Cc, c = i % Cc;
    const float* g = (which == 0) ? gq : (which == 1) ? gk : gv;
    const float* be = (which == 0) ? bq : (which == 1) ? bk : bv;
    const float* mu = (which == 0) ? mq : (which == 1) ? mk : mv;
    const float* va = (which == 0) ? vq : (which == 1) ? vk : vv;
    float inv = g[c] * rsqrtf(va[c] + EPSf);
    bn[which * 768 + c] = inv;
    bn[which * 768 + 384 + c] = be[c] - mu[c] * inv;
  }
  if (i < Bn * Cc) {                                  // cls token -> row 0
    int b = i / Cc, c = i % Cc;
    unsigned short v = f2bf(hidden[(size_t)b * LQ * Cc + c]);
    q_act[(size_t)b * LQ * Cc + c] = v;
    k_act[(size_t)b * LKV * Cc + c] = v;
    v_act[(size_t)b * LKV * Cc + c] = v;
  }
}

// ---------------- fused depthwise convs, LDS weights + q-weight reg hoist -----
// r15 base (all weights in LDS, 71 us). This round: q weights (36 of the 72
// per-thread ds_reads) hoisted ONCE from LDS into wq_[9] registers after the
// barrier. Unlike r16 (global source -> compiler re-materialized flat loads),
// an LDS source degrades gracefully: either regs hold (saves ~40k LDS cyc/CU)
// or the compiler re-reads LDS per use (= r15 status quo). kv weights stay in
// LDS (27 vectors resident = r14's proven spill).
__global__ __launch_bounds__(256) void conv_fused_kernel(
    const float* hidden, const float* wT, const float* bn,
    unsigned short* q_act, unsigned short* k_act, unsigned short* v_act) {
  __shared__ __align__(16) float wlds[27 * 32];      // [tap][32 ch]
  __shared__ __align__(16) float bnlds[6 * 32];      // qinv,qadd,kinv,kadd,vinv,vadd
  int tid = threadIdx.x;
  int bid = blockIdx.x;
  int cgrp = bid % 12; int r = bid / 12;
  int band = r % 8; int b = r / 8;
  int cbase = cgrp * 32;

  // stage weight slice + bn slice (one-time, coalesced)
  for (int idx = tid; idx < 27 * 32; idx += 256)
    wlds[idx] = wT[(idx >> 5) * Cc + cbase + (idx & 31)];
  if (tid < 6 * 32) {
    int a = tid >> 5, cl = tid & 31;
    bnlds[tid] = bn[(a >> 1) * 768 + (a & 1) * 384 + cbase + cl];
  }
  __syncthreads();

  int cgsub = tid & 7, j = tid >> 3;                 // lanes: 8 ch-groups x 8 j
  int cl = cgsub * 4;                                // channel within slice
  int c = cbase + cl;
  int i0 = band * 4;

  f32x4 wq_[9];                                      // q weights: LDS -> regs once
#pragma unroll
  for (int t = 0; t < 9; ++t) wq_[t] = *(const f32x4*)&wlds[t * 32 + cl];

  const f32x4 fz = {0.f, 0.f, 0.f, 0.f};
  f32x4 accq[4] = {fz, fz, fz, fz};
  f32x4 k0 = fz, k1 = fz, v0 = fz, v1 = fz;
  const float* hb = hidden + (size_t)b * LQ * Cc + Cc + c;
#pragma unroll
  for (int dh = 0; dh < 6; ++dh) {
    int h = i0 - 1 + dh;
    if (h < 0 || h >= Hh) continue;                  // block-uniform
    const float* hr = hb + (size_t)(h * Ww + j) * Cc;
    f32x4 xl = *(const f32x4*)(hr - Cc);             // in-bounds even at j==0
    f32x4 xc = *(const f32x4*)hr;
    f32x4 xr = (j < Ww - 1) ? *(const f32x4*)(hr + Cc) : fz;
    if (j == 0) xl = fz;
#pragma unroll
    for (int dy = 0; dy < 3; ++dy) {
      int oi = dh - dy;                              // compile-time
      if (oi >= 0 && oi < 4)
        accq[oi] += wq_[dy * 3 + 0] * xl + wq_[dy * 3 + 1] * xc + wq_[dy * 3 + 2] * xr;
    }
    if (dh <= 2) {                                   // kv row 2*band, dy = dh
      k0 += *(const f32x4*)&wlds[(9 + dh * 3 + 0) * 32 + cl] * xl +
            *(const f32x4*)&wlds[(9 + dh * 3 + 1) * 32 + cl] * xc +
            *(const f32x4*)&wlds[(9 + dh * 3 + 2) * 32 + cl] * xr;
      v0 += *(const f32x4*)&wlds[(18 + dh * 3 + 0) * 32 + cl] * xl +
            *(const f32x4*)&wlds[(18 + dh * 3 + 1) * 32 + cl] * xc +
            *(const f32x4*)&wlds[(18 + dh * 3 + 2) * 32 + cl] * xr;
    }
    if (dh >= 2 && dh <= 4) {                        // kv row 2*band+1, dy = dh-2
      int dy2 = dh - 2;
      k1 += *(const f32x4*)&wlds[(9 + dy2 * 3 + 0) * 32 + cl] * xl +
            *(const f32x4*)&wlds[(9 + dy2 * 3 + 1) * 32 + cl] * xc +
            *(const f32x4*)&wlds[(9 + dy2 * 3 + 2) * 32 + cl] * xr;
      v1 += *(const f32x4*)&wlds[(18 + dy2 * 3 + 0) * 32 + cl] * xl +
            *(const f32x4*)&wlds[(18 + dy2 * 3 + 1) * 32 + cl] * xc +
            *(const f32x4*)&wlds[(18 + dy2 * 3 + 2) * 32 + cl] * xr;
    }
  }
  f32x4 invq = *(const f32x4*)&bnlds[0 * 32 + cl];
  f32x4 addq = *(const f32x4*)&bnlds[1 * 32 + cl];
#pragma unroll
  for (int oi = 0; oi < 4; ++oi) {
    int pos = (i0 + oi) * Ww + j;
    *(u16x4*)&q_act[((size_t)b * LQ + 1 + pos) * Cc + c] = f4tobf(accq[oi], invq, addq);
  }
  if ((j & 1) == 0) {
    f32x4 invk = *(const f32x4*)&bnlds[2 * 32 + cl];
    f32x4 addk = *(const f32x4*)&bnlds[3 * 32 + cl];
    f32x4 invv = *(const f32x4*)&bnlds[4 * 32 + cl];
    f32x4 addv = *(const f32x4*)&bnlds[5 * 32 + cl];
    int jk = j >> 1;
    int p0 = (band * 2) * 16 + jk;
    int p1 = (band * 2 + 1) * 16 + jk;
    *(u16x4*)&k_act[((size_t)b * LKV + 1 + p0) * Cc + c] = f4tobf(k0, invk, addk);
    *(u16x4*)&k_act[((size_t)b * LKV + 1 + p1) * Cc + c] = f4tobf(k1, invk, addk);
    *(u16x4*)&v_act[((size_t)b * LKV + 1 + p0) * Cc + c] = f4tobf(v0, invv, addv);
    *(u16x4*)&v_act[((size_t)b * LKV + 1 + p1) * Cc + c] = f4tobf(v1, invv, addv);
  }
}

// ---------------- fused projection GEMMs, 4-buffer counted-vmcnt pipeline -----
// 2313 logical blocks: [0,1539) q (513 mt x 3 nt, mt-major); [1539,1926) k;
// [1926,2313) v. Bijective XCD-chunk swizzle (nwg=2313=8*289+1).
// BK=32, 4 LDS buffers, STAGE(t+2) per step, vmcnt(8) counted wait, one raw
// barrier per step (4-buffer distance makes write-vs-lagging-read race-free).
__global__ __launch_bounds__(256) void proj_all_kernel(
    const unsigned short* q_act, const unsigned short* k_act,
    const unsigned short* v_act, const unsigned short* wbf,
    const float* bq, const float* bk, const float* bv,
    unsigned short* q_proj, unsigned short* k_proj, unsigned short* v_norm) {
  __shared__ __align__(16) unsigned short A_s[4][128 * 32];
  __shared__ __align__(16) unsigned short B_s[4][128 * 32];

  int orig = blockIdx.x;
  int xcd = orig & 7, jj = orig >> 3;                  // m204 bijective swizzle
  int wg = (xcd == 0 ? 0 : 290 + (xcd - 1) * 289) + jj;

  const unsigned short *A, *Wb;
  const float* bias;
  unsigned short* outp;
  int M, mode, mt, nt;
  if (wg < 1539) {
    mt = wg / 3; nt = wg % 3;
    A = q_act; Wb = wbf; bias = bq; outp = q_proj; M = Bn * LQ; mode = 0;
  } else if (wg < 1926) {
    int r2 = wg - 1539; mt = r2 / 3; nt = r2 % 3;
    A = k_act; Wb = wbf + Cc * Cc; bias = bk; outp = k_proj; M = Bn * LKV; mode = 1;
  } else {
    int r2 = wg - 1926; mt = r2 / 3; nt = r2 % 3;
    A = v_act; Wb = wbf + 2 * Cc * Cc; bias = bv; outp = v_norm; M = Bn * LKV; mode = 1;
  }
  int m0 = mt * 128, n0 = nt * 128;
  int tid = threadIdx.x, lane = tid & 63, wid = tid >> 6;
  int wm = wid >> 1, wn = wid & 1;
  int lr = lane & 15, lg = lane >> 4;

  const f32x4 fz = {0.f, 0.f, 0.f, 0.f};
  f32x4 acc[4][4];
#pragma unroll
  for (int i = 0; i < 4; ++i)
#pragma unroll
    for (int j = 0; j < 4; ++j) acc[i][j] = fz;

  // staging: chunk = 16 rows x 64 B; 8 chunks/buffer; wave stages 2 chunks.
  int cr = lane >> 2;                              // row in chunk
  int scol = ((lane & 3) ^ ((cr >> 1) & 3)) << 3;  // inverse-swizzled source col

#define STAGE(bufi, kk)                                                        \
  {                                                                            \
    _Pragma("unroll")                                                          \
    for (int i_ = 0; i_ < 2; ++i_) {                                           \
      int chunk = wid * 2 + i_;                                                \
      int arow = m0 + chunk * 16 + cr;                                         \
      if (arow > M - 1) arow = M - 1;                                          \
      __builtin_amdgcn_global_load_lds(                                        \
          (const __attribute__((address_space(1))) void*)                      \
              &A[(size_t)arow * Cc + (kk) + scol],                             \
          (__attribute__((address_space(3))) void*)&A_s[bufi][chunk * 512],    \
          16, 0, 0);                                                           \
      int brow = n0 + chunk * 16 + cr;                                         \
      __builtin_amdgcn_global_load_lds(                                        \
          (const __attribute__((address_space(1))) void*)                      \
              &Wb[(size_t)brow * Cc + (kk) + scol],                            \
          (__attribute__((address_space(3))) void*)&B_s[bufi][chunk * 512],    \
          16, 0, 0);                                                           \
    }                                                                          \
  }

  STAGE(0, 0);
  STAGE(1, 32);

#pragma unroll
  for (int t = 0; t < 12; ++t) {
    if (t < 10) STAGE((t + 2) & 3, (t + 2) * 32);
    // counted wait: 2 stages (8 loads) stay in flight; never drain to 0 mid-loop
    if (t < 10)       asm volatile("s_waitcnt vmcnt(8)" ::: "memory");
    else if (t == 10) asm volatile("s_waitcnt vmcnt(4)" ::: "memory");
    else              asm volatile("s_waitcnt vmcnt(0)" ::: "memory");
    __builtin_amdgcn_s_barrier();

    const unsigned short* As = &A_s[t & 3][0];
    const unsigned short* Bs = &B_s[t & 3][0];
    u16x8 af[4], bf2[4];
#pragma unroll
    for (int mi = 0; mi < 4; ++mi) {
      int r = wm * 64 + mi * 16 + lr;
      af[mi] = *(const u16x8*)((const char*)As + r * 64 +
                               ((lg ^ ((r >> 1) & 3)) << 4));
    }
#pragma unroll
    for (int ni = 0; ni < 4; ++ni) {
      int r = wn * 64 + ni * 16 + lr;
      bf2[ni] = *(const u16x8*)((const char*)Bs + r * 64 +
                                ((lg ^ ((r >> 1) & 3)) << 4));
    }
#pragma unroll
    for (int mi = 0; mi < 4; ++mi)
#pragma unroll
      for (int ni = 0; ni < 4; ++ni)
        mfma_16x16x32_bf16(acc[mi][ni], af[mi], bf2[ni]);
  }
#undef STAGE

  // epilogue: ni-innermost -> 4 consecutive 32B stores fill 128B per row
  float bvv[4];
#pragma unroll
  for (int ni = 0; ni < 4; ++ni) bvv[ni] = bias[n0 + wn * 64 + ni * 16 + lr];
#pragma unroll
  for (int mi = 0; mi < 4; ++mi) {
#pragma unroll
    for (int rg = 0; rg < 4; ++rg) {
      int row = m0 + wm * 64 + mi * 16 + lg * 4 + rg;
      if (row < M) {
        size_t rbase;
        if (mode == 0) {
          rbase = (size_t)row * Cc;
        } else {
          int bb = row / LKV, t2 = row % LKV;
          rbase = ((size_t)bb * TPAD + t2) * Cc;
        }
#pragma unroll
        for (int ni = 0; ni < 4; ++ni) {
          int col = n0 + wn * 64 + ni * 16 + lr;
          outp[rbase + col] = f2bf(acc[mi][ni][rg] + bvv[ni]);
        }
      }
    }
  }
}

// ---------------- fused attention: 8-wave blocks, K+V in LDS, in-reg P --------
// grid (4, NH, B); block = 512 thr (8 waves). 74.75 KB LDS -> 2 blocks/CU.
// Round-10-proven layout (bank-conflict arc closed: r11/r13 swizzle variants
// measured SLOWER despite fewer conflicts — write conflicts are one-time
// staging cost absorbed by TLP; extra read-address VALU is not).
__global__ __launch_bounds__(512) void attn_kernel(
    const unsigned short* q_proj, const unsigned short* k_proj,
    const unsigned short* v_norm, float* out) {
  __shared__ __align__(16) unsigned short K_s[288 * 64];
  __shared__ __align__(16) unsigned short V_s[64][296];
  int tid = threadIdx.x;
  int wid = tid >> 6, lane = tid & 63;
  int lr = lane & 15, lg = lane >> 4;
  int h = blockIdx.y, b = blockIdx.z, bx = blockIdx.x;

  // ---- K staging: 2176 x 16B chunks (t < 272) ----
  const unsigned short* kg = k_proj + (size_t)b * TPAD * Cc + h * HD;
#pragma unroll
  for (int i = 0; i < 5; ++i) {
    int c = tid + i * 512;
    if (c < 2176) {
      int row = c >> 3, c16 = c & 7;
      u16x8 kv = *(const u16x8*)&kg[(size_t)row * Cc + c16 * 8];
      *(u16x8*)((char*)K_s + row * 128 + ((c16 * 16) ^ ((row & 7) << 4))) = kv;
    }
  }
  // ---- V staging with transpose: chunk c -> t=c>>3, d-block=c&7 ----
  const unsigned short* vg = v_norm + (size_t)b * TPAD * Cc + h * HD;
  const u16x8 uz = {0, 0, 0, 0, 0, 0, 0, 0};
#pragma unroll
  for (int i = 0; i < 5; ++i) {
    int c = tid + i * 512;
    if (c < 2304) {
      int t = c >> 3, dch = c & 7;
      u16x8 val = (t < LKV) ? *(const u16x8*)&vg[(size_t)t * Cc + dch * 8] : uz;
#pragma unroll
      for (int j = 0; j < 8; ++j) V_s[dch * 8 + j][t] = val[j];
    }
  }
  __syncthreads();

  int start = (bx == 0) ? 0 : 1 + bx * 16;            // 65 = 17+16+16+16
  int end = 17 + bx * 16;
  const f32x4 fz = {0.f, 0.f, 0.f, 0.f};

  for (int qt = start + wid; qt < end; qt += 8) {
    int qbase = qt * 16;
    int qrow = qbase + lr; if (qrow > LQ - 1) qrow = LQ - 1;
    const u16x8* qp =
        (const u16x8*)&q_proj[((size_t)b * LQ + qrow) * Cc + h * HD + lg * 8];
    u16x8 q0 = qp[0], q1 = qp[4];

    // ---- QK^T swapped: lane (lr,lg) holds s for q=lr, t = 16T + lg*4 + rg ----
    // T=17 (t>=272) is fully masked -> skipped entirely.
    int kb0 = lr * 128 + ((lg * 16) ^ ((lr & 7) << 4));
    int kb1 = kb0 ^ 64;
    f32x4 s[17];
    __builtin_amdgcn_s_setprio(1);
#pragma unroll
    for (int T = 0; T < 17; ++T) {
      u16x8 ka = *(const u16x8*)((const char*)K_s + kb0 + T * 2048);
      u16x8 kc = *(const u16x8*)((const char*)K_s + kb1 + T * 2048);
      s[T] = fz;
      mfma_16x16x32_bf16(s[T], ka, q0);
      mfma_16x16x32_bf16(s[T], kc, q1);
    }
    __builtin_amdgcn_s_setprio(0);

    // ---- softmax over t for this lane's q-row (round-7-proven form) ----
    float m = -1e30f;
#pragma unroll
    for (int T = 0; T < 17; ++T)
#pragma unroll
      for (int rg = 0; rg < 4; ++rg) {
        int t = T * 16 + lg * 4 + rg;
        float v = (t < LKV) ? s[T][rg] * SCALEf : -1e30f;
        s[T][rg] = v;
        m = fmaxf(m, v);
      }
    m = fmaxf(m, __shfl_xor(m, 16, 64));
    m = fmaxf(m, __shfl_xor(m, 32, 64));
    float sum = 0.f;
#pragma unroll
    for (int T = 0; T < 17; ++T)
#pragma unroll
      for (int rg = 0; rg < 4; ++rg) {
        float p = __expf(s[T][rg] - m);               // masked -> 0
        s[T][rg] = p;
        sum += p;
      }
    sum += __shfl_xor(sum, 16, 64);
    sum += __shfl_xor(sum, 32, 64);

    // ---- PV: in-register P relayout (cvt_pk + permlane swaps), V from LDS ----
    f32x4 o[4];
#pragma unroll
    for (int dt = 0; dt < 4; ++dt) o[dt] = fz;
    __builtin_amdgcn_s_setprio(1);
#pragma unroll
    for (int kk = 0; kk < 9; ++kk) {
      int c00, c01, c10, c11;
      asm("v_cvt_pk_bf16_f32 %0, %1, %2"
          : "=v"(c00) : "v"(s[2 * kk][0]), "v"(s[2 * kk][1]));
      asm("v_cvt_pk_bf16_f32 %0, %1, %2"
          : "=v"(c01) : "v"(s[2 * kk][2]), "v"(s[2 * kk][3]));
      if (kk < 8) {
        asm("v_cvt_pk_bf16_f32 %0, %1, %2"
            : "=v"(c10) : "v"(s[2 * kk + 1][0]), "v"(s[2 * kk + 1][1]));
        asm("v_cvt_pk_bf16_f32 %0, %1, %2"
            : "=v"(c11) : "v"(s[2 * kk + 1][2]), "v"(s[2 * kk + 1][3]));
      } else {
        c10 = 0; c11 = 0;                             // t in [272,288): P = 0
      }
      asm("v_permlane32_swap_b32 %0, %1" : "+v"(c00), "+v"(c10));
      asm("v_permlane32_swap_b32 %0, %1" : "+v"(c01), "+v"(c11));
      asm("v_permlane16_swap_b32 %0, %1" : "+v"(c00), "+v"(c10));
      asm("v_permlane16_swap_b32 %0, %1" : "+v"(c01), "+v"(c11));
      i32x4 pv = {c00, c01, c10, c11};
      u16x8 pa = __builtin_bit_cast(u16x8, pv);
#pragma unroll
      for (int dt = 0; dt < 4; ++dt) {
        u16x8 vb = *(const u16x8*)&V_s[dt * 16 + lr][kk * 32 + lg * 8];
        mfma_16x16x32_bf16(o[dt], pa, vb);
      }
    }
    __builtin_amdgcn_s_setprio(0);

    // ---- epilogue: o col=d=lr, row=q=lg*4+rg ----
    float rs = 1.0f / sum;
#pragma unroll
    for (int rg = 0; rg < 4; ++rg) {
      int row = qbase + lg * 4 + rg;
      float rsv = __shfl(rs, lg * 4 + rg, 64);
      if (row <= LQ - 1) {
#pragma unroll
        for (int dt = 0; dt < 4; ++dt)
          out[((size_t)b * LQ + row) * Cc + h * HD + dt * 16 + lr] = o[dt][rg] * rsv;
      }
    }
  }
}

extern "C" void kernel_launch(void* const* d_in, const int* in_sizes, int n_in,
                              void* d_out, int out_size, void* d_ws, size_t ws_size,
                              hipStream_t stream) {
  const float* hidden   = (const float*)d_in[0];
  const float* conv_q_w = (const float*)d_in[1];
  const float* bn_q_g   = (const float*)d_in[2];
  const float* bn_q_b   = (const float*)d_in[3];
  const float* bn_q_m   = (const float*)d_in[4];
  const float* bn_q_v   = (const float*)d_in[5];
  const float* w_q      = (const float*)d_in[6];
  const float* b_q      = (const float*)d_in[7];
  const float* conv_k_w = (const float*)d_in[8];
  const float* bn_k_g   = (const float*)d_in[9];
  const float* bn_k_b   = (const float*)d_in[10];
  const float* bn_k_m   = (const float*)d_in[11];
  const float* bn_k_v   = (const float*)d_in[12];
  const float* w_k      = (const float*)d_in[13];
  const float* b_k      = (const float*)d_in[14];
  const float* conv_v_w = (const float*)d_in[15];
  const float* bn_v_g   = (const float*)d_in[16];
  const float* bn_v_b   = (const float*)d_in[17];
  const float* bn_v_m   = (const float*)d_in[18];
  const float* bn_v_v   = (const float*)d_in[19];
  const float* w_v      = (const float*)d_in[20];
  const float* b_v      = (const float*)d_in[21];
  float* out = (float*)d_out;

  char* ws = (char*)d_ws;
  unsigned short* q_act  = (unsigned short*)(ws + 0);          // 65600*384
  unsigned short* k_act  = (unsigned short*)(ws + 50380800);   // 16448*384
  unsigned short* v_act  = (unsigned short*)(ws + 63012864);   // 16448*384
  unsigned short* q_proj = (unsigned short*)(ws + 75644928);   // 65600*384
  unsigned short* k_proj = (unsigned short*)(ws + 126025728);  // 64*288*384
  unsigned short* v_norm = (unsigned short*)(ws + 140181504);  // 64*288*384
  unsigned short* wbf    = (unsigned short*)(ws + 154337280);  // 3*384*384
  float*          wT     = (float*)(ws + 155222016);           // 3*9*384 f32
  float*          bnp    = (float*)(ws + 155263488);           // 3*2*384 f32

  prep_kernel<<<(3 * Cc * Cc) / 256, 256, 0, stream>>>(hidden,
      w_q, w_k, w_v, conv_q_w, conv_k_w, conv_v_w,
      bn_q_g, bn_q_b, bn_q_m, bn_q_v,
      bn_k_g, bn_k_b, bn_k_m, bn_k_v,
      bn_v_g, bn_v_b, bn_v_m, bn_v_v,
      wbf, wT, bnp, q_act, k_act, v_act);
  conv_fused_kernel<<<Bn * 8 * 12, 256, 0, stream>>>(
      hidden, wT, bnp, q_act, k_act, v_act);

  proj_all_kernel<<<2313, 256, 0, stream>>>(
      q_act, k_act, v_act, wbf, b_q, b_k, b_v, q_proj, k_proj, v_norm);

  dim3 ga(4, NHh, Bn);
  attn_kernel<<<ga, 512, 0, stream>>>(q_proj, k_proj, v_norm, out);
}

// Round 19
// 179.329 us; speedup vs baseline: 1.0336x; 1.0336x over previous
//
#include <hip/hip_runtime.h>

#define Bn 64
#define Cc 384
#define NHh 6
#define HD 64
#define Hh 32
#define Ww 32
#define LQ 1025
#define LKV 257
#define TPAD 288
#define EPSf 1e-5f
#define SCALEf 0.05103103630798288f   // 384^-0.5

typedef float f32x4 __attribute__((ext_vector_type(4)));
typedef unsigned short u16x8 __attribute__((ext_vector_type(8)));
typedef unsigned short u16x4 __attribute__((ext_vector_type(4)));
typedef int i32x4 __attribute__((ext_vector_type(4)));

__device__ __forceinline__ void mfma_16x16x32_bf16(f32x4& d, u16x8 a, u16x8 b) {
  // D = A*B + D ; A: 16x32, row = lane&15, k = (lane>>4)*8 + i (contig 8)
  //              B: 32x16, col = lane&15, k = (lane>>4)*8 + i
  //              D: col = lane&15, row = (lane>>4)*4 + reg
  asm("v_mfma_f32_16x16x32_bf16 %0, %1, %2, %0" : "+v"(d) : "v"(a), "v"(b));
}

__device__ __forceinline__ unsigned short f2bf(float f) {
  unsigned int u = __builtin_bit_cast(unsigned int, f);
  u += 0x7fffu + ((u >> 16) & 1u);
  return (unsigned short)(u >> 16);
}

__device__ __forceinline__ u16x4 f4tobf(f32x4 v, f32x4 inv, f32x4 add) {
  u16x4 r;
#pragma unroll
  for (int i = 0; i < 4; ++i) r[i] = f2bf(v[i] * inv[i] + add[i]);
  return r;
}

// ---------------- merged prep: weight cvt + conv-w prep + cls -----------------
__global__ void prep_kernel(const float* hidden,
                            const float* wq, const float* wk, const float* wv,
                            const float* cwq, const float* cwk, const float* cwv,
                            const float* gq, const float* bq, const float* mq, const float* vq,
                            const float* gk, const float* bk, const float* mk, const float* vk,
                            const float* gv, const float* bv, const float* mv, const float* vv,
                            unsigned short* wbf, float* wT, float* bn,
                            unsigned short* q_act, unsigned short* k_act,
                            unsigned short* v_act) {
  int i = blockIdx.x * 256 + threadIdx.x;            // grid = 3*Cc*Cc = 442368
  if (i < 3 * Cc * Cc) {                              // GEMM weights -> bf16
    int which = i / (Cc * Cc), r = i % (Cc * Cc);
    const float* s = (which == 0) ? wq : (which == 1) ? wk : wv;
    wbf[i] = f2bf(s[r]);
  }
  if (i < 3 * 9 * Cc) {                               // conv weight transpose
    int which = i / (9 * Cc), r = i % (9 * Cc), t = r / Cc, c = r % Cc;
    const float* s = (which == 0) ? cwq : (which == 1) ? cwk : cwv;
    wT[(which * 9 + t) * Cc + c] = s[c * 9 + t];
  }
  if (i < 3 * Cc) {                                   // BN fold
    int which = i / Cc, c = i % Cc;
    const float* g = (which == 0) ? gq : (which == 1) ? gk : gv;
    const float* be = (which == 0) ? bq : (which == 1) ? bk : bv;
    const float* mu = (which == 0) ? mq : (which == 1) ? mk : mv;
    const float* va = (which == 0) ? vq : (which == 1) ? vk : vv;
    float inv = g[c] * rsqrtf(va[c] + EPSf);
    bn[which * 768 + c] = inv;
    bn[which * 768 + 384 + c] = be[c] - mu[c] * inv;
  }
  if (i < Bn * Cc) {                                  // cls token -> row 0
    int b = i / Cc, c = i % Cc;
    unsigned short v = f2bf(hidden[(size_t)b * LQ * Cc + c]);
    q_act[(size_t)b * LQ * Cc + c] = v;
    k_act[(size_t)b * LKV * Cc + c] = v;
    v_act[(size_t)b * LKV * Cc + c] = v;
  }
}

// ---------------- fused depthwise convs, LDS-resident weights (r15-proven) ----
// Storage-class tradeoff probed at 4 points: 27 weight vectors in regs -> spill
// (r14, 98 us); 9 in regs from global -> re-materialized (r16, 80 us); 9 in
// regs from LDS -> VGPR 52, occupancy 36%, still slower (r18, 79 us); ALL
// weights in LDS per-use -> 71 us, VGPR 40, occupancy 51% (r15/r17). In this
// latency-bound kernel occupancy beats per-thread op count. Arc closed.
__global__ __launch_bounds__(256) void conv_fused_kernel(
    const float* hidden, const float* wT, const float* bn,
    unsigned short* q_act, unsigned short* k_act, unsigned short* v_act) {
  __shared__ __align__(16) float wlds[27 * 32];      // [tap][32 ch]
  __shared__ __align__(16) float bnlds[6 * 32];      // qinv,qadd,kinv,kadd,vinv,vadd
  int tid = threadIdx.x;
  int bid = blockIdx.x;
  int cgrp = bid % 12; int r = bid / 12;
  int band = r % 8; int b = r / 8;
  int cbase = cgrp * 32;

  // stage weight slice + bn slice (one-time, coalesced)
  for (int idx = tid; idx < 27 * 32; idx += 256)
    wlds[idx] = wT[(idx >> 5) * Cc + cbase + (idx & 31)];
  if (tid < 6 * 32) {
    int a = tid >> 5, cl = tid & 31;
    bnlds[tid] = bn[(a >> 1) * 768 + (a & 1) * 384 + cbase + cl];
  }
  __syncthreads();

  int cgsub = tid & 7, j = tid >> 3;                 // lanes: 8 ch-groups x 8 j
  int cl = cgsub * 4;                                // channel within slice
  int c = cbase + cl;
  int i0 = band * 4;

  const f32x4 fz = {0.f, 0.f, 0.f, 0.f};
  f32x4 accq[4] = {fz, fz, fz, fz};
  f32x4 k0 = fz, k1 = fz, v0 = fz, v1 = fz;
  const float* hb = hidden + (size_t)b * LQ * Cc + Cc + c;
#pragma unroll
  for (int dh = 0; dh < 6; ++dh) {
    int h = i0 - 1 + dh;
    if (h < 0 || h >= Hh) continue;                  // block-uniform
    const float* hr = hb + (size_t)(h * Ww + j) * Cc;
    f32x4 xl = *(const f32x4*)(hr - Cc);             // in-bounds even at j==0
    f32x4 xc = *(const f32x4*)hr;
    f32x4 xr = (j < Ww - 1) ? *(const f32x4*)(hr + Cc) : fz;
    if (j == 0) xl = fz;
#pragma unroll
    for (int dy = 0; dy < 3; ++dy) {
      int oi = dh - dy;                              // compile-time
      if (oi >= 0 && oi < 4)
        accq[oi] += *(const f32x4*)&wlds[(dy * 3 + 0) * 32 + cl] * xl +
                    *(const f32x4*)&wlds[(dy * 3 + 1) * 32 + cl] * xc +
                    *(const f32x4*)&wlds[(dy * 3 + 2) * 32 + cl] * xr;
    }
    if (dh <= 2) {                                   // kv row 2*band, dy = dh
      k0 += *(const f32x4*)&wlds[(9 + dh * 3 + 0) * 32 + cl] * xl +
            *(const f32x4*)&wlds[(9 + dh * 3 + 1) * 32 + cl] * xc +
            *(const f32x4*)&wlds[(9 + dh * 3 + 2) * 32 + cl] * xr;
      v0 += *(const f32x4*)&wlds[(18 + dh * 3 + 0) * 32 + cl] * xl +
            *(const f32x4*)&wlds[(18 + dh * 3 + 1) * 32 + cl] * xc +
            *(const f32x4*)&wlds[(18 + dh * 3 + 2) * 32 + cl] * xr;
    }
    if (dh >= 2 && dh <= 4) {                        // kv row 2*band+1, dy = dh-2
      int dy2 = dh - 2;
      k1 += *(const f32x4*)&wlds[(9 + dy2 * 3 + 0) * 32 + cl] * xl +
            *(const f32x4*)&wlds[(9 + dy2 * 3 + 1) * 32 + cl] * xc +
            *(const f32x4*)&wlds[(9 + dy2 * 3 + 2) * 32 + cl] * xr;
      v1 += *(const f32x4*)&wlds[(18 + dy2 * 3 + 0) * 32 + cl] * xl +
            *(const f32x4*)&wlds[(18 + dy2 * 3 + 1) * 32 + cl] * xc +
            *(const f32x4*)&wlds[(18 + dy2 * 3 + 2) * 32 + cl] * xr;
    }
  }
  f32x4 invq = *(const f32x4*)&bnlds[0 * 32 + cl];
  f32x4 addq = *(const f32x4*)&bnlds[1 * 32 + cl];
#pragma unroll
  for (int oi = 0; oi < 4; ++oi) {
    int pos = (i0 + oi) * Ww + j;
    *(u16x4*)&q_act[((size_t)b * LQ + 1 + pos) * Cc + c] = f4tobf(accq[oi], invq, addq);
  }
  if ((j & 1) == 0) {
    f32x4 invk = *(const f32x4*)&bnlds[2 * 32 + cl];
    f32x4 addk = *(const f32x4*)&bnlds[3 * 32 + cl];
    f32x4 invv = *(const f32x4*)&bnlds[4 * 32 + cl];
    f32x4 addv = *(const f32x4*)&bnlds[5 * 32 + cl];
    int jk = j >> 1;
    int p0 = (band * 2) * 16 + jk;
    int p1 = (band * 2 + 1) * 16 + jk;
    *(u16x4*)&k_act[((size_t)b * LKV + 1 + p0) * Cc + c] = f4tobf(k0, invk, addk);
    *(u16x4*)&k_act[((size_t)b * LKV + 1 + p1) * Cc + c] = f4tobf(k1, invk, addk);
    *(u16x4*)&v_act[((size_t)b * LKV + 1 + p0) * Cc + c] = f4tobf(v0, invv, addv);
    *(u16x4*)&v_act[((size_t)b * LKV + 1 + p1) * Cc + c] = f4tobf(v1, invv, addv);
  }
}

// ---------------- fused projection GEMMs, 4-buffer counted-vmcnt pipeline -----
// 2313 logical blocks: [0,1539) q (513 mt x 3 nt, mt-major); [1539,1926) k;
// [1926,2313) v. Bijective XCD-chunk swizzle (nwg=2313=8*289+1).
// BK=32, 4 LDS buffers, STAGE(t+2) per step, vmcnt(8) counted wait, one raw
// barrier per step (4-buffer distance makes write-vs-lagging-read race-free).
__global__ __launch_bounds__(256) void proj_all_kernel(
    const unsigned short* q_act, const unsigned short* k_act,
    const unsigned short* v_act, const unsigned short* wbf,
    const float* bq, const float* bk, const float* bv,
    unsigned short* q_proj, unsigned short* k_proj, unsigned short* v_norm) {
  __shared__ __align__(16) unsigned short A_s[4][128 * 32];
  __shared__ __align__(16) unsigned short B_s[4][128 * 32];

  int orig = blockIdx.x;
  int xcd = orig & 7, jj = orig >> 3;                  // m204 bijective swizzle
  int wg = (xcd == 0 ? 0 : 290 + (xcd - 1) * 289) + jj;

  const unsigned short *A, *Wb;
  const float* bias;
  unsigned short* outp;
  int M, mode, mt, nt;
  if (wg < 1539) {
    mt = wg / 3; nt = wg % 3;
    A = q_act; Wb = wbf; bias = bq; outp = q_proj; M = Bn * LQ; mode = 0;
  } else if (wg < 1926) {
    int r2 = wg - 1539; mt = r2 / 3; nt = r2 % 3;
    A = k_act; Wb = wbf + Cc * Cc; bias = bk; outp = k_proj; M = Bn * LKV; mode = 1;
  } else {
    int r2 = wg - 1926; mt = r2 / 3; nt = r2 % 3;
    A = v_act; Wb = wbf + 2 * Cc * Cc; bias = bv; outp = v_norm; M = Bn * LKV; mode = 1;
  }
  int m0 = mt * 128, n0 = nt * 128;
  int tid = threadIdx.x, lane = tid & 63, wid = tid >> 6;
  int wm = wid >> 1, wn = wid & 1;
  int lr = lane & 15, lg = lane >> 4;

  const f32x4 fz = {0.f, 0.f, 0.f, 0.f};
  f32x4 acc[4][4];
#pragma unroll
  for (int i = 0; i < 4; ++i)
#pragma unroll
    for (int j = 0; j < 4; ++j) acc[i][j] = fz;

  // staging: chunk = 16 rows x 64 B; 8 chunks/buffer; wave stages 2 chunks.
  int cr = lane >> 2;                              // row in chunk
  int scol = ((lane & 3) ^ ((cr >> 1) & 3)) << 3;  // inverse-swizzled source col

#define STAGE(bufi, kk)                                                        \
  {                                                                            \
    _Pragma("unroll")                                                          \
    for (int i_ = 0; i_ < 2; ++i_) {                                           \
      int chunk = wid * 2 + i_;                                                \
      int arow = m0 + chunk * 16 + cr;                                         \
      if (arow > M - 1) arow = M - 1;                                          \
      __builtin_amdgcn_global_load_lds(                                        \
          (const __attribute__((address_space(1))) void*)                      \
              &A[(size_t)arow * Cc + (kk) + scol],                             \
          (__attribute__((address_space(3))) void*)&A_s[bufi][chunk * 512],    \
          16, 0, 0);                                                           \
      int brow = n0 + chunk * 16 + cr;                                         \
      __builtin_amdgcn_global_load_lds(                                        \
          (const __attribute__((address_space(1))) void*)                      \
              &Wb[(size_t)brow * Cc + (kk) + scol],                            \
          (__attribute__((address_space(3))) void*)&B_s[bufi][chunk * 512],    \
          16, 0, 0);                                                           \
    }                                                                          \
  }

  STAGE(0, 0);
  STAGE(1, 32);

#pragma unroll
  for (int t = 0; t < 12; ++t) {
    if (t < 10) STAGE((t + 2) & 3, (t + 2) * 32);
    // counted wait: 2 stages (8 loads) stay in flight; never drain to 0 mid-loop
    if (t < 10)       asm volatile("s_waitcnt vmcnt(8)" ::: "memory");
    else if (t == 10) asm volatile("s_waitcnt vmcnt(4)" ::: "memory");
    else              asm volatile("s_waitcnt vmcnt(0)" ::: "memory");
    __builtin_amdgcn_s_barrier();

    const unsigned short* As = &A_s[t & 3][0];
    const unsigned short* Bs = &B_s[t & 3][0];
    u16x8 af[4], bf2[4];
#pragma unroll
    for (int mi = 0; mi < 4; ++mi) {
      int r = wm * 64 + mi * 16 + lr;
      af[mi] = *(const u16x8*)((const char*)As + r * 64 +
                               ((lg ^ ((r >> 1) & 3)) << 4));
    }
#pragma unroll
    for (int ni = 0; ni < 4; ++ni) {
      int r = wn * 64 + ni * 16 + lr;
      bf2[ni] = *(const u16x8*)((const char*)Bs + r * 64 +
                                ((lg ^ ((r >> 1) & 3)) << 4));
    }
#pragma unroll
    for (int mi = 0; mi < 4; ++mi)
#pragma unroll
      for (int ni = 0; ni < 4; ++ni)
        mfma_16x16x32_bf16(acc[mi][ni], af[mi], bf2[ni]);
  }
#undef STAGE

  // epilogue: ni-innermost -> 4 consecutive 32B stores fill 128B per row
  float bvv[4];
#pragma unroll
  for (int ni = 0; ni < 4; ++ni) bvv[ni] = bias[n0 + wn * 64 + ni * 16 + lr];
#pragma unroll
  for (int mi = 0; mi < 4; ++mi) {
#pragma unroll
    for (int rg = 0; rg < 4; ++rg) {
      int row = m0 + wm * 64 + mi * 16 + lg * 4 + rg;
      if (row < M) {
        size_t rbase;
        if (mode == 0) {
          rbase = (size_t)row * Cc;
        } else {
          int bb = row / LKV, t2 = row % LKV;
          rbase = ((size_t)bb * TPAD + t2) * Cc;
        }
#pragma unroll
        for (int ni = 0; ni < 4; ++ni) {
          int col = n0 + wn * 64 + ni * 16 + lr;
          outp[rbase + col] = f2bf(acc[mi][ni][rg] + bvv[ni]);
        }
      }
    }
  }
}

// ---------------- fused attention: 8-wave blocks, K+V in LDS, in-reg P --------
// grid (4, NH, B); block = 512 thr (8 waves). 74.75 KB LDS -> 2 blocks/CU.
// Round-10-proven layout (bank-conflict arc closed: r11/r13 swizzle variants
// measured SLOWER despite fewer conflicts — write conflicts are one-time
// staging cost absorbed by TLP; extra read-address VALU is not).
__global__ __launch_bounds__(512) void attn_kernel(
    const unsigned short* q_proj, const unsigned short* k_proj,
    const unsigned short* v_norm, float* out) {
  __shared__ __align__(16) unsigned short K_s[288 * 64];
  __shared__ __align__(16) unsigned short V_s[64][296];
  int tid = threadIdx.x;
  int wid = tid >> 6, lane = tid & 63;
  int lr = lane & 15, lg = lane >> 4;
  int h = blockIdx.y, b = blockIdx.z, bx = blockIdx.x;

  // ---- K staging: 2176 x 16B chunks (t < 272) ----
  const unsigned short* kg = k_proj + (size_t)b * TPAD * Cc + h * HD;
#pragma unroll
  for (int i = 0; i < 5; ++i) {
    int c = tid + i * 512;
    if (c < 2176) {
      int row = c >> 3, c16 = c & 7;
      u16x8 kv = *(const u16x8*)&kg[(size_t)row * Cc + c16 * 8];
      *(u16x8*)((char*)K_s + row * 128 + ((c16 * 16) ^ ((row & 7) << 4))) = kv;
    }
  }
  // ---- V staging with transpose: chunk c -> t=c>>3, d-block=c&7 ----
  const unsigned short* vg = v_norm + (size_t)b * TPAD * Cc + h * HD;
  const u16x8 uz = {0, 0, 0, 0, 0, 0, 0, 0};
#pragma unroll
  for (int i = 0; i < 5; ++i) {
    int c = tid + i * 512;
    if (c < 2304) {
      int t = c >> 3, dch = c & 7;
      u16x8 val = (t < LKV) ? *(const u16x8*)&vg[(size_t)t * Cc + dch * 8] : uz;
#pragma unroll
      for (int j = 0; j < 8; ++j) V_s[dch * 8 + j][t] = val[j];
    }
  }
  __syncthreads();

  int start = (bx == 0) ? 0 : 1 + bx * 16;            // 65 = 17+16+16+16
  int end = 17 + bx * 16;
  const f32x4 fz = {0.f, 0.f, 0.f, 0.f};

  for (int qt = start + wid; qt < end; qt += 8) {
    int qbase = qt * 16;
    int qrow = qbase + lr; if (qrow > LQ - 1) qrow = LQ - 1;
    const u16x8* qp =
        (const u16x8*)&q_proj[((size_t)b * LQ + qrow) * Cc + h * HD + lg * 8];
    u16x8 q0 = qp[0], q1 = qp[4];

    // ---- QK^T swapped: lane (lr,lg) holds s for q=lr, t = 16T + lg*4 + rg ----
    // T=17 (t>=272) is fully masked -> skipped entirely.
    int kb0 = lr * 128 + ((lg * 16) ^ ((lr & 7) << 4));
    int kb1 = kb0 ^ 64;
    f32x4 s[17];
    __builtin_amdgcn_s_setprio(1);
#pragma unroll
    for (int T = 0; T < 17; ++T) {
      u16x8 ka = *(const u16x8*)((const char*)K_s + kb0 + T * 2048);
      u16x8 kc = *(const u16x8*)((const char*)K_s + kb1 + T * 2048);
      s[T] = fz;
      mfma_16x16x32_bf16(s[T], ka, q0);
      mfma_16x16x32_bf16(s[T], kc, q1);
    }
    __builtin_amdgcn_s_setprio(0);

    // ---- softmax over t for this lane's q-row (round-7-proven form) ----
    float m = -1e30f;
#pragma unroll
    for (int T = 0; T < 17; ++T)
#pragma unroll
      for (int rg = 0; rg < 4; ++rg) {
        int t = T * 16 + lg * 4 + rg;
        float v = (t < LKV) ? s[T][rg] * SCALEf : -1e30f;
        s[T][rg] = v;
        m = fmaxf(m, v);
      }
    m = fmaxf(m, __shfl_xor(m, 16, 64));
    m = fmaxf(m, __shfl_xor(m, 32, 64));
    float sum = 0.f;
#pragma unroll
    for (int T = 0; T < 17; ++T)
#pragma unroll
      for (int rg = 0; rg < 4; ++rg) {
        float p = __expf(s[T][rg] - m);               // masked -> 0
        s[T][rg] = p;
        sum += p;
      }
    sum += __shfl_xor(sum, 16, 64);
    sum += __shfl_xor(sum, 32, 64);

    // ---- PV: in-register P relayout (cvt_pk + permlane swaps), V from LDS ----
    f32x4 o[4];
#pragma unroll
    for (int dt = 0; dt < 4; ++dt) o[dt] = fz;
    __builtin_amdgcn_s_setprio(1);
#pragma unroll
    for (int kk = 0; kk < 9; ++kk) {
      int c00, c01, c10, c11;
      asm("v_cvt_pk_bf16_f32 %0, %1, %2"
          : "=v"(c00) : "v"(s[2 * kk][0]), "v"(s[2 * kk][1]));
      asm("v_cvt_pk_bf16_f32 %0, %1, %2"
          : "=v"(c01) : "v"(s[2 * kk][2]), "v"(s[2 * kk][3]));
      if (kk < 8) {
        asm("v_cvt_pk_bf16_f32 %0, %1, %2"
            : "=v"(c10) : "v"(s[2 * kk + 1][0]), "v"(s[2 * kk + 1][1]));
        asm("v_cvt_pk_bf16_f32 %0, %1, %2"
            : "=v"(c11) : "v"(s[2 * kk + 1][2]), "v"(s[2 * kk + 1][3]));
      } else {
        c10 = 0; c11 = 0;                             // t in [272,288): P = 0
      }
      asm("v_permlane32_swap_b32 %0, %1" : "+v"(c00), "+v"(c10));
      asm("v_permlane32_swap_b32 %0, %1" : "+v"(c01), "+v"(c11));
      asm("v_permlane16_swap_b32 %0, %1" : "+v"(c00), "+v"(c10));
      asm("v_permlane16_swap_b32 %0, %1" : "+v"(c01), "+v"(c11));
      i32x4 pv = {c00, c01, c10, c11};
      u16x8 pa = __builtin_bit_cast(u16x8, pv);
#pragma unroll
      for (int dt = 0; dt < 4; ++dt) {
        u16x8 vb = *(const u16x8*)&V_s[dt * 16 + lr][kk * 32 + lg * 8];
        mfma_16x16x32_bf16(o[dt], pa, vb);
      }
    }
    __builtin_amdgcn_s_setprio(0);

    // ---- epilogue: o col=d=lr, row=q=lg*4+rg ----
    float rs = 1.0f / sum;
#pragma unroll
    for (int rg = 0; rg < 4; ++rg) {
      int row = qbase + lg * 4 + rg;
      float rsv = __shfl(rs, lg * 4 + rg, 64);
      if (row <= LQ - 1) {
#pragma unroll
        for (int dt = 0; dt < 4; ++dt)
          out[((size_t)b * LQ + row) * Cc + h * HD + dt * 16 + lr] = o[dt][rg] * rsv;
      }
    }
  }
}

extern "C" void kernel_launch(void* const* d_in, const int* in_sizes, int n_in,
                              void* d_out, int out_size, void* d_ws, size_t ws_size,
                              hipStream_t stream) {
  const float* hidden   = (const float*)d_in[0];
  const float* conv_q_w = (const float*)d_in[1];
  const float* bn_q_g   = (const float*)d_in[2];
  const float* bn_q_b   = (const float*)d_in[3];
  const float* bn_q_m   = (const float*)d_in[4];
  const float* bn_q_v   = (const float*)d_in[5];
  const float* w_q      = (const float*)d_in[6];
  const float* b_q      = (const float*)d_in[7];
  const float* conv_k_w = (const float*)d_in[8];
  const float* bn_k_g   = (const float*)d_in[9];
  const float* bn_k_b   = (const float*)d_in[10];
  const float* bn_k_m   = (const float*)d_in[11];
  const float* bn_k_v   = (const float*)d_in[12];
  const float* w_k      = (const float*)d_in[13];
  const float* b_k      = (const float*)d_in[14];
  const float* conv_v_w = (const float*)d_in[15];
  const float* bn_v_g   = (const float*)d_in[16];
  const float* bn_v_b   = (const float*)d_in[17];
  const float* bn_v_m   = (const float*)d_in[18];
  const float* bn_v_v   = (const float*)d_in[19];
  const float* w_v      = (const float*)d_in[20];
  const float* b_v      = (const float*)d_in[21];
  float* out = (float*)d_out;

  char* ws = (char*)d_ws;
  unsigned short* q_act  = (unsigned short*)(ws + 0);          // 65600*384
  unsigned short* k_act  = (unsigned short*)(ws + 50380800);   // 16448*384
  unsigned short* v_act  = (unsigned short*)(ws + 63012864);   // 16448*384
  unsigned short* q_proj = (unsigned short*)(ws + 75644928);   // 65600*384
  unsigned short* k_proj = (unsigned short*)(ws + 126025728);  // 64*288*384
  unsigned short* v_norm = (unsigned short*)(ws + 140181504);  // 64*288*384
  unsigned short* wbf    = (unsigned short*)(ws + 154337280);  // 3*384*384
  float*          wT     = (float*)(ws + 155222016);           // 3*9*384 f32
  float*          bnp    = (float*)(ws + 155263488);           // 3*2*384 f32

  prep_kernel<<<(3 * Cc * Cc) / 256, 256, 0, stream>>>(hidden,
      w_q, w_k, w_v, conv_q_w, conv_k_w, conv_v_w,
      bn_q_g, bn_q_b, bn_q_m, bn_q_v,
      bn_k_g, bn_k_b, bn_k_m, bn_k_v,
      bn_v_g, bn_v_b, bn_v_m, bn_v_v,
      wbf, wT, bnp, q_act, k_act, v_act);
  conv_fused_kernel<<<Bn * 8 * 12, 256, 0, stream>>>(
      hidden, wT, bnp, q_act, k_act, v_act);

  proj_all_kernel<<<2313, 256, 0, stream>>>(
      q_act, k_act, v_act, wbf, b_q, b_k, b_v, q_proj, k_proj, v_norm);

  dim3 ga(4, NHh, Bn);
  attn_kernel<<<ga, 512, 0, stream>>>(q_proj, k_proj, v_norm, out);
}